// Round 1
// baseline (3940.416 us; speedup 1.0000x reference)
//
#include <hip/hip_runtime.h>
#include <stdint.h>

#define NB 8
#define NPT 16384
#define NM 1024
#define NK 32

// ws layout (float element offsets)
#define WS_W0T 0                    // 67*64 = 4288   W0t[c][o] = W0[o][c]*s0[o]
#define WS_B0  (WS_W0T + 4288)      // 64             b0*s0+t0
#define WS_W1T (WS_B0 + 64)         // 64*128 = 8192
#define WS_B1  (WS_W1T + 8192)      // 128
#define WS_W2T (WS_B1 + 128)        // 128*256 = 32768
#define WS_B2  (WS_W2T + 32768)     // 256
#define WS_IDX (WS_B2 + 256)        // 8192 ints (FPS indices)
#define WS_NXYZ (WS_IDX + 8192)     // 8*1024*3 = 24576 floats
#define WS_BALL (WS_NXYZ + 24576)   // 8*1024*32 = 262144 ints

// out layout (float element offsets)
#define OUT_XYZ 0
#define OUT_FEAT 24576
#define OUT_IDX (24576 + 2097152)

// ---------------- weight prep: transpose + fold BN scale ----------------
__global__ void prep_weights(const float* __restrict__ W0, const float* __restrict__ b0,
                             const float* __restrict__ s0, const float* __restrict__ t0,
                             const float* __restrict__ W1, const float* __restrict__ b1,
                             const float* __restrict__ s1, const float* __restrict__ t1,
                             const float* __restrict__ W2, const float* __restrict__ b2,
                             const float* __restrict__ s2, const float* __restrict__ t2,
                             float* __restrict__ ws) {
    int id = blockIdx.x * 256 + threadIdx.x;
    if (id < 4288) { int c = id >> 6, o = id & 63;  ws[WS_W0T + id] = W0[o * 67 + c] * s0[o]; return; }
    id -= 4288;
    if (id < 64)   { ws[WS_B0 + id] = fmaf(b0[id], s0[id], t0[id]); return; }
    id -= 64;
    if (id < 8192) { int c = id >> 7, o = id & 127; ws[WS_W1T + id] = W1[o * 64 + c] * s1[o]; return; }
    id -= 8192;
    if (id < 128)  { ws[WS_B1 + id] = fmaf(b1[id], s1[id], t1[id]); return; }
    id -= 128;
    if (id < 32768){ int c = id >> 8, o = id & 255; ws[WS_W2T + id] = W2[o * 128 + c] * s2[o]; return; }
    id -= 32768;
    if (id < 256)  { ws[WS_B2 + id] = fmaf(b2[id], s2[id], t2[id]); return; }
}

// ---------------- farthest point sampling ----------------
// One block per batch; 1024 threads; each thread owns 16 strided points in registers.
// Distance math uses _rn intrinsics (no FMA) to bit-match the numpy/XLA reference;
// argmax tie-break = lowest index (lexicographic reduction).
__global__ __launch_bounds__(1024) void fps_kernel(const float* __restrict__ xyz,
                                                   int* __restrict__ out_idx) {
    int b = blockIdx.x, t = threadIdx.x;
    const float* Xp = xyz + (size_t)b * NPT * 3;
    float px[16], py[16], pz[16], dd[16];
#pragma unroll
    for (int j = 0; j < 16; j++) {
        int p = t + j * 1024;
        px[j] = Xp[p * 3 + 0]; py[j] = Xp[p * 3 + 1]; pz[j] = Xp[p * 3 + 2];
        dd[j] = 1e10f;
    }
    __shared__ float s_val[16];
    __shared__ int   s_idx[16];
    __shared__ int   s_best;
    int farthest = 0;
    for (int it = 0; it < NM; ++it) {
        if (t == 0) out_idx[b * NM + it] = farthest;
        // broadcast centroid load (same address across wave -> 1 txn, L1-hit)
        float cx = Xp[farthest * 3 + 0];
        float cy = Xp[farthest * 3 + 1];
        float cz = Xp[farthest * 3 + 2];
        float best = -1.0f; int bi = 0x7fffffff;
#pragma unroll
        for (int j = 0; j < 16; j++) {
            float dx = __fsub_rn(px[j], cx);
            float dy = __fsub_rn(py[j], cy);
            float dz = __fsub_rn(pz[j], cz);
            float d  = __fadd_rn(__fadd_rn(__fmul_rn(dx, dx), __fmul_rn(dy, dy)), __fmul_rn(dz, dz));
            float dn = fminf(dd[j], d);
            dd[j] = dn;
            if (dn > best) { best = dn; bi = t + j * 1024; }  // ascending j => first-max wins in-thread
        }
        // wave argmax (64 lanes), tie -> lower index
#pragma unroll
        for (int off = 32; off >= 1; off >>= 1) {
            float ov = __shfl_xor(best, off);
            int   oi = __shfl_xor(bi, off);
            if (ov > best || (ov == best && oi < bi)) { best = ov; bi = oi; }
        }
        int w = t >> 6;
        if ((t & 63) == 0) { s_val[w] = best; s_idx[w] = bi; }
        __syncthreads();
        if (t < 64) {
            float v = (t < 16) ? s_val[t] : -1.0f;
            int   i2 = (t < 16) ? s_idx[t] : 0x7fffffff;
#pragma unroll
            for (int off = 8; off >= 1; off >>= 1) {
                float ov = __shfl_xor(v, off);
                int   oi = __shfl_xor(i2, off);
                if (ov > v || (ov == v && oi < i2)) { v = ov; i2 = oi; }
            }
            if (t == 0) s_best = i2;
        }
        __syncthreads();
        farthest = s_best;
    }
}

// ---------------- gather new_xyz + emit indices as float ----------------
__global__ void gather_newxyz(const float* __restrict__ xyz, const int* __restrict__ idx_ws,
                              float* __restrict__ nxyz_ws, float* __restrict__ out_xyz,
                              float* __restrict__ out_idx_f) {
    int id = blockIdx.x * 256 + threadIdx.x;
    if (id >= NB * NM) return;
    int b = id / NM;
    int p = idx_ws[id];
    const float* Xp = xyz + ((size_t)b * NPT + p) * 3;
    float x = Xp[0], y = Xp[1], z = Xp[2];
    nxyz_ws[id * 3 + 0] = x; nxyz_ws[id * 3 + 1] = y; nxyz_ws[id * 3 + 2] = z;
    out_xyz[id * 3 + 0] = x; out_xyz[id * 3 + 1] = y; out_xyz[id * 3 + 2] = z;
    out_idx_f[id] = (float)p;
}

// ---------------- ball query: first 32 in-radius indices (ascending) ----------------
__global__ __launch_bounds__(256) void ball_query_kernel(const float* __restrict__ xyz,
                                                         const float* __restrict__ nxyz,
                                                         int* __restrict__ ball) {
    int blk = blockIdx.x;
    int b = blk >> 10;
    int t = threadIdx.x;
    const float* Xp = xyz + (size_t)b * NPT * 3;
    float cx = nxyz[blk * 3 + 0], cy = nxyz[blk * 3 + 1], cz = nxyz[blk * 3 + 2];
    const float r2 = (float)(0.4 * 0.4);
    uint64_t mask = 0;
    int base = t * 64;
    for (int j = 0; j < 64; j++) {
        int p = base + j;
        float dx = __fsub_rn(Xp[p * 3 + 0], cx);
        float dy = __fsub_rn(Xp[p * 3 + 1], cy);
        float dz = __fsub_rn(Xp[p * 3 + 2], cz);
        float d2 = __fadd_rn(__fadd_rn(__fmul_rn(dx, dx), __fmul_rn(dy, dy)), __fmul_rn(dz, dz));
        if (d2 <= r2) mask |= (1ull << j);
    }
    int cnt = __popcll(mask);
    int scan = cnt;                       // wave inclusive scan
    for (int off = 1; off < 64; off <<= 1) {
        int nv = __shfl_up(scan, off);
        if ((t & 63) >= off) scan += nv;
    }
    __shared__ int s_wsum[4];
    __shared__ int s_hit[32];
    int w = t >> 6;
    if ((t & 63) == 63) s_wsum[w] = scan;
    __syncthreads();
    int woff = 0;
    for (int i = 0; i < 4; i++) if (i < w) woff += s_wsum[i];
    int excl = woff + scan - cnt;         // exclusive prefix in point-index order
    uint64_t mm = mask; int pos = excl;
    while (mm && pos < 32) {
        int j = __ffsll((long long)mm) - 1;
        s_hit[pos] = base + j;
        pos++;
        mm &= mm - 1;
    }
    __syncthreads();
    int total = s_wsum[0] + s_wsum[1] + s_wsum[2] + s_wsum[3];
    if (t < 32) {
        int first = s_hit[0];             // total >= 1 (center itself at d2=0)
        ball[blk * NK + t] = (t < total) ? s_hit[t] : first;
    }
}

// ---------------- fused group + 3xMLP + max over K ----------------
// One block per (b,m); 256 threads; thread (g = t>>5, k = t&31).
__global__ __launch_bounds__(256) void fused_mlp_kernel(const float* __restrict__ xyz,
                                                        const float* __restrict__ feats,
                                                        const float* __restrict__ ws_f,
                                                        const int* __restrict__ ball,
                                                        const float* __restrict__ nxyz,
                                                        float* __restrict__ out_feat) {
    int blk = blockIdx.x;
    int b = blk >> 10, m = blk & 1023;
    int t = threadIdx.x;
    int k = t & 31, g = t >> 5;  // g in 0..7
    __shared__ float Xs[67][32];
    __shared__ float h1[64][32];
    __shared__ float h2[128][32];
    __shared__ int sidx[32];
    const float* W0t = ws_f + WS_W0T; const float* b0f = ws_f + WS_B0;
    const float* W1t = ws_f + WS_W1T; const float* b1f = ws_f + WS_B1;
    const float* W2t = ws_f + WS_W2T; const float* b2f = ws_f + WS_B2;

    if (t < 32) sidx[t] = ball[blk * NK + t];
    __syncthreads();

    const float* Xp = xyz + (size_t)b * NPT * 3;
    if (g < 3) {
        float cc = nxyz[blk * 3 + g];
        Xs[g][k] = Xp[sidx[k] * 3 + g] - cc;
    }
    const float* Fp = feats + (size_t)b * 64 * NPT;
#pragma unroll
    for (int i = 0; i < 8; i++) {
        int c = g + 8 * i;
        Xs[3 + c][k] = Fp[(size_t)c * NPT + sidx[k]];
    }
    __syncthreads();

    // layer 1: 67 -> 64, thread computes o = g*8 + [0..8)
    {
        float acc[8];
#pragma unroll
        for (int i = 0; i < 8; i++) acc[i] = b0f[g * 8 + i];
        for (int c = 0; c < 67; c++) {
            float xv = Xs[c][k];
            const float* wr = W0t + c * 64 + g * 8;
            float4 wa = *(const float4*)(wr), wb = *(const float4*)(wr + 4);
            acc[0] = fmaf(wa.x, xv, acc[0]); acc[1] = fmaf(wa.y, xv, acc[1]);
            acc[2] = fmaf(wa.z, xv, acc[2]); acc[3] = fmaf(wa.w, xv, acc[3]);
            acc[4] = fmaf(wb.x, xv, acc[4]); acc[5] = fmaf(wb.y, xv, acc[5]);
            acc[6] = fmaf(wb.z, xv, acc[6]); acc[7] = fmaf(wb.w, xv, acc[7]);
        }
#pragma unroll
        for (int i = 0; i < 8; i++) h1[g * 8 + i][k] = fmaxf(acc[i], 0.0f);
    }
    __syncthreads();

    // layer 2: 64 -> 128, o = g*16 + [0..16)
    {
        float acc[16];
#pragma unroll
        for (int i = 0; i < 16; i++) acc[i] = b1f[g * 16 + i];
        for (int c = 0; c < 64; c++) {
            float xv = h1[c][k];
            const float4* wr = (const float4*)(W1t + c * 128 + g * 16);
#pragma unroll
            for (int q = 0; q < 4; q++) {
                float4 wv = wr[q];
                acc[q * 4 + 0] = fmaf(wv.x, xv, acc[q * 4 + 0]);
                acc[q * 4 + 1] = fmaf(wv.y, xv, acc[q * 4 + 1]);
                acc[q * 4 + 2] = fmaf(wv.z, xv, acc[q * 4 + 2]);
                acc[q * 4 + 3] = fmaf(wv.w, xv, acc[q * 4 + 3]);
            }
        }
#pragma unroll
        for (int i = 0; i < 16; i++) h2[g * 16 + i][k] = fmaxf(acc[i], 0.0f);
    }
    __syncthreads();

    // layer 3: 128 -> 256, o = g*32 + [0..32), then max over k (32-lane group reduce)
    {
        float acc[32];
#pragma unroll
        for (int i = 0; i < 32; i++) acc[i] = b2f[g * 32 + i];
        for (int c = 0; c < 128; c++) {
            float xv = h2[c][k];
            const float4* wr = (const float4*)(W2t + c * 256 + g * 32);
#pragma unroll
            for (int q = 0; q < 8; q++) {
                float4 wv = wr[q];
                acc[q * 4 + 0] = fmaf(wv.x, xv, acc[q * 4 + 0]);
                acc[q * 4 + 1] = fmaf(wv.y, xv, acc[q * 4 + 1]);
                acc[q * 4 + 2] = fmaf(wv.z, xv, acc[q * 4 + 2]);
                acc[q * 4 + 3] = fmaf(wv.w, xv, acc[q * 4 + 3]);
            }
        }
#pragma unroll
        for (int i = 0; i < 32; i++) {
            float v = fmaxf(acc[i], 0.0f);
#pragma unroll
            for (int off = 16; off >= 1; off >>= 1) v = fmaxf(v, __shfl_xor(v, off));
            if (k == 0) out_feat[((size_t)b * 256 + g * 32 + i) * NM + m] = v;
        }
    }
}

extern "C" void kernel_launch(void* const* d_in, const int* in_sizes, int n_in,
                              void* d_out, int out_size, void* d_ws, size_t ws_size,
                              hipStream_t stream) {
    const float* xyz   = (const float*)d_in[0];
    const float* feats = (const float*)d_in[1];
    const float* W0 = (const float*)d_in[2];  const float* b0 = (const float*)d_in[3];
    const float* s0 = (const float*)d_in[4];  const float* t0 = (const float*)d_in[5];
    const float* W1 = (const float*)d_in[6];  const float* b1 = (const float*)d_in[7];
    const float* s1 = (const float*)d_in[8];  const float* t1 = (const float*)d_in[9];
    const float* W2 = (const float*)d_in[10]; const float* b2 = (const float*)d_in[11];
    const float* s2 = (const float*)d_in[12]; const float* t2 = (const float*)d_in[13];

    float* ws_f = (float*)d_ws;
    int*   idx_ws  = (int*)(ws_f + WS_IDX);
    float* nxyz_ws = ws_f + WS_NXYZ;
    int*   ball_ws = (int*)(ws_f + WS_BALL);

    float* out_f = (float*)d_out;
    float* out_xyz  = out_f + OUT_XYZ;
    float* out_feat = out_f + OUT_FEAT;
    float* out_idxf = out_f + OUT_IDX;

    fps_kernel<<<NB, 1024, 0, stream>>>(xyz, idx_ws);
    prep_weights<<<179, 256, 0, stream>>>(W0, b0, s0, t0, W1, b1, s1, t1, W2, b2, s2, t2, ws_f);
    gather_newxyz<<<32, 256, 0, stream>>>(xyz, idx_ws, nxyz_ws, out_xyz, out_idxf);
    ball_query_kernel<<<NB * NM, 256, 0, stream>>>(xyz, nxyz_ws, ball_ws);
    fused_mlp_kernel<<<NB * NM, 256, 0, stream>>>(xyz, feats, ws_f, ball_ws, nxyz_ws, out_feat);
}

// Round 2
// 3291.722 us; speedup vs baseline: 1.1971x; 1.1971x over previous
//
#include <hip/hip_runtime.h>
#include <stdint.h>

#define NB 8
#define NPT 16384
#define NM 1024
#define NK 32

// ws layout (float element offsets)
#define WS_W0T 0                    // 67*64 = 4288   W0t[c][o] = W0[o][c]*s0[o]
#define WS_B0  (WS_W0T + 4288)      // 64             b0*s0+t0
#define WS_W1T (WS_B0 + 64)         // 64*128 = 8192
#define WS_B1  (WS_W1T + 8192)      // 128
#define WS_W2T (WS_B1 + 128)        // 128*256 = 32768
#define WS_B2  (WS_W2T + 32768)     // 256
#define WS_IDX (WS_B2 + 256)        // 8192 ints (FPS indices)
#define WS_NXYZ (WS_IDX + 8192)     // 8*1024*3 = 24576 floats
#define WS_BALL (WS_NXYZ + 24576)   // 8*1024*32 = 262144 ints

// out layout (float element offsets)
#define OUT_XYZ 0
#define OUT_FEAT 24576
#define OUT_IDX (24576 + 2097152)

// ---------------- weight prep: transpose + fold BN scale ----------------
__global__ void prep_weights(const float* __restrict__ W0, const float* __restrict__ b0,
                             const float* __restrict__ s0, const float* __restrict__ t0,
                             const float* __restrict__ W1, const float* __restrict__ b1,
                             const float* __restrict__ s1, const float* __restrict__ t1,
                             const float* __restrict__ W2, const float* __restrict__ b2,
                             const float* __restrict__ s2, const float* __restrict__ t2,
                             float* __restrict__ ws) {
    int id = blockIdx.x * 256 + threadIdx.x;
    if (id < 4288) { int c = id >> 6, o = id & 63;  ws[WS_W0T + id] = W0[o * 67 + c] * s0[o]; return; }
    id -= 4288;
    if (id < 64)   { ws[WS_B0 + id] = fmaf(b0[id], s0[id], t0[id]); return; }
    id -= 64;
    if (id < 8192) { int c = id >> 7, o = id & 127; ws[WS_W1T + id] = W1[o * 64 + c] * s1[o]; return; }
    id -= 8192;
    if (id < 128)  { ws[WS_B1 + id] = fmaf(b1[id], s1[id], t1[id]); return; }
    id -= 128;
    if (id < 32768){ int c = id >> 8, o = id & 255; ws[WS_W2T + id] = W2[o * 128 + c] * s2[o]; return; }
    id -= 32768;
    if (id < 256)  { ws[WS_B2 + id] = fmaf(b2[id], s2[id], t2[id]); return; }
}

// ---------------- farthest point sampling ----------------
// One block per batch, 512 threads x 32 strided points in registers.
// Single barrier per iteration:
//   - per-point (dist, ~idx) packed into u64; wave argmax = unsigned max (tie -> lower idx)
//   - 8 wave leaders write s_red[parity][w]; ONE __syncthreads(); every thread
//     max-reduces the 8 values itself => all threads know `farthest` (no 2nd barrier).
//   - parity double-buffer makes the next iteration's leader writes race-free.
//   - centroid re-fetched via same-address broadcast load (L2-hit), off the barrier path.
// Distance math uses _rn intrinsics (no FMA contraction) to bit-match the reference.
__global__ __launch_bounds__(512) void fps_kernel(const float* __restrict__ xyz,
                                                  int* __restrict__ out_idx) {
    int b = blockIdx.x, t = threadIdx.x;
    const float* __restrict__ Xp = xyz + (size_t)b * NPT * 3;
    float px[32], py[32], pz[32], dd[32];
#pragma unroll
    for (int j = 0; j < 32; j++) {
        int p = t + j * 512;
        px[j] = Xp[p * 3 + 0]; py[j] = Xp[p * 3 + 1]; pz[j] = Xp[p * 3 + 2];
        dd[j] = 1e10f;
    }
    __shared__ uint64_t s_red[2][8];
    int farthest = 0;
    float cx = Xp[0], cy = Xp[1], cz = Xp[2];
    for (int it = 0; it < NM; ++it) {
        if (t == 0) out_idx[b * NM + it] = farthest;
        float best = -1.0f; int bi = 0;
#pragma unroll
        for (int j = 0; j < 32; j++) {
            float dx = __fsub_rn(px[j], cx);
            float dy = __fsub_rn(py[j], cy);
            float dz = __fsub_rn(pz[j], cz);
            float d  = __fadd_rn(__fadd_rn(__fmul_rn(dx, dx), __fmul_rn(dy, dy)), __fmul_rn(dz, dz));
            float dn = fminf(dd[j], d);
            dd[j] = dn;
            if (dn > best) { best = dn; bi = t + j * 512; }  // ascending j => first-max wins in-thread
        }
        // pack: high32 = dist bits (positive floats sort as uints), low32 = ~idx (tie -> lower idx)
        uint64_t pk = ((uint64_t)__float_as_uint(best) << 32) | (uint64_t)(uint32_t)(~(uint32_t)bi);
#pragma unroll
        for (int off = 32; off >= 1; off >>= 1) {
            uint64_t o = __shfl_xor(pk, off);
            if (o > pk) pk = o;
        }
        if ((t & 63) == 0) s_red[it & 1][t >> 6] = pk;
        __syncthreads();
        uint64_t m0 = s_red[it & 1][0];
#pragma unroll
        for (int w = 1; w < 8; w++) { uint64_t o = s_red[it & 1][w]; if (o > m0) m0 = o; }
        int widx = (int)(~(uint32_t)m0);
        farthest = widx;
        const float* cp = Xp + (size_t)widx * 3;   // same addr across wave -> broadcast, L2-hit
        cx = cp[0]; cy = cp[1]; cz = cp[2];
    }
}

// ---------------- gather new_xyz + emit indices as float ----------------
__global__ void gather_newxyz(const float* __restrict__ xyz, const int* __restrict__ idx_ws,
                              float* __restrict__ nxyz_ws, float* __restrict__ out_xyz,
                              float* __restrict__ out_idx_f) {
    int id = blockIdx.x * 256 + threadIdx.x;
    if (id >= NB * NM) return;
    int b = id / NM;
    int p = idx_ws[id];
    const float* Xp = xyz + ((size_t)b * NPT + p) * 3;
    float x = Xp[0], y = Xp[1], z = Xp[2];
    nxyz_ws[id * 3 + 0] = x; nxyz_ws[id * 3 + 1] = y; nxyz_ws[id * 3 + 2] = z;
    out_xyz[id * 3 + 0] = x; out_xyz[id * 3 + 1] = y; out_xyz[id * 3 + 2] = z;
    out_idx_f[id] = (float)p;
}

// ---------------- ball query: first 32 in-radius indices (ascending) ----------------
// Thread t owns contiguous points [t*64, t*64+64); loads them as 3xfloat4 per 4 points
// (768B/thread is 16B-aligned). Hit mask -> block prefix scan -> first 32 in order.
__global__ __launch_bounds__(256) void ball_query_kernel(const float* __restrict__ xyz,
                                                         const float* __restrict__ nxyz,
                                                         int* __restrict__ ball) {
    int blk = blockIdx.x;
    int b = blk >> 10;
    int t = threadIdx.x;
    const float* Xp = xyz + (size_t)b * NPT * 3;
    float cx = nxyz[blk * 3 + 0], cy = nxyz[blk * 3 + 1], cz = nxyz[blk * 3 + 2];
    const float r2 = (float)(0.4 * 0.4);
    uint64_t mask = 0;
    int base = t * 64;
    const float4* q = (const float4*)(Xp + (size_t)base * 3);
#pragma unroll 4
    for (int c = 0; c < 16; c++) {
        float4 A = q[c * 3 + 0], B = q[c * 3 + 1], C = q[c * 3 + 2];
        float xs[4] = {A.x, A.w, B.z, C.y};
        float ys[4] = {A.y, B.x, B.w, C.z};
        float zs[4] = {A.z, B.y, C.x, C.w};
#pragma unroll
        for (int u = 0; u < 4; u++) {
            float dx = __fsub_rn(xs[u], cx);
            float dy = __fsub_rn(ys[u], cy);
            float dz = __fsub_rn(zs[u], cz);
            float d2 = __fadd_rn(__fadd_rn(__fmul_rn(dx, dx), __fmul_rn(dy, dy)), __fmul_rn(dz, dz));
            if (d2 <= r2) mask |= (1ull << (c * 4 + u));
        }
    }
    int cnt = __popcll(mask);
    int scan = cnt;                       // wave inclusive scan
    for (int off = 1; off < 64; off <<= 1) {
        int nv = __shfl_up(scan, off);
        if ((t & 63) >= off) scan += nv;
    }
    __shared__ int s_wsum[4];
    __shared__ int s_hit[32];
    int w = t >> 6;
    if ((t & 63) == 63) s_wsum[w] = scan;
    __syncthreads();
    int woff = 0;
    for (int i = 0; i < 4; i++) if (i < w) woff += s_wsum[i];
    int excl = woff + scan - cnt;         // exclusive prefix in point-index order
    uint64_t mm = mask; int pos = excl;
    while (mm && pos < 32) {
        int j = __ffsll((long long)mm) - 1;
        s_hit[pos] = base + j;
        pos++;
        mm &= mm - 1;
    }
    __syncthreads();
    int total = s_wsum[0] + s_wsum[1] + s_wsum[2] + s_wsum[3];
    if (t < 32) {
        int first = s_hit[0];             // total >= 1 (center itself at d2=0)
        ball[blk * NK + t] = (t < total) ? s_hit[t] : first;
    }
}

// ---------------- fused group + 3xMLP + max over K ----------------
// One block per (b,m); 256 threads; thread (g = t>>5, k = t&31).
__global__ __launch_bounds__(256) void fused_mlp_kernel(const float* __restrict__ xyz,
                                                        const float* __restrict__ feats,
                                                        const float* __restrict__ ws_f,
                                                        const int* __restrict__ ball,
                                                        const float* __restrict__ nxyz,
                                                        float* __restrict__ out_feat) {
    int blk = blockIdx.x;
    int b = blk >> 10, m = blk & 1023;
    int t = threadIdx.x;
    int k = t & 31, g = t >> 5;  // g in 0..7
    __shared__ float Xs[67][32];
    __shared__ float h1[64][32];
    __shared__ float h2[128][32];
    __shared__ int sidx[32];
    const float* W0t = ws_f + WS_W0T; const float* b0f = ws_f + WS_B0;
    const float* W1t = ws_f + WS_W1T; const float* b1f = ws_f + WS_B1;
    const float* W2t = ws_f + WS_W2T; const float* b2f = ws_f + WS_B2;

    if (t < 32) sidx[t] = ball[blk * NK + t];
    __syncthreads();

    const float* Xp = xyz + (size_t)b * NPT * 3;
    if (g < 3) {
        float cc = nxyz[blk * 3 + g];
        Xs[g][k] = Xp[sidx[k] * 3 + g] - cc;
    }
    const float* Fp = feats + (size_t)b * 64 * NPT;
#pragma unroll
    for (int i = 0; i < 8; i++) {
        int c = g + 8 * i;
        Xs[3 + c][k] = Fp[(size_t)c * NPT + sidx[k]];
    }
    __syncthreads();

    // layer 1: 67 -> 64, thread computes o = g*8 + [0..8)
    {
        float acc[8];
#pragma unroll
        for (int i = 0; i < 8; i++) acc[i] = b0f[g * 8 + i];
        for (int c = 0; c < 67; c++) {
            float xv = Xs[c][k];
            const float* wr = W0t + c * 64 + g * 8;
            float4 wa = *(const float4*)(wr), wb = *(const float4*)(wr + 4);
            acc[0] = fmaf(wa.x, xv, acc[0]); acc[1] = fmaf(wa.y, xv, acc[1]);
            acc[2] = fmaf(wa.z, xv, acc[2]); acc[3] = fmaf(wa.w, xv, acc[3]);
            acc[4] = fmaf(wb.x, xv, acc[4]); acc[5] = fmaf(wb.y, xv, acc[5]);
            acc[6] = fmaf(wb.z, xv, acc[6]); acc[7] = fmaf(wb.w, xv, acc[7]);
        }
#pragma unroll
        for (int i = 0; i < 8; i++) h1[g * 8 + i][k] = fmaxf(acc[i], 0.0f);
    }
    __syncthreads();

    // layer 2: 64 -> 128, o = g*16 + [0..16)
    {
        float acc[16];
#pragma unroll
        for (int i = 0; i < 16; i++) acc[i] = b1f[g * 16 + i];
        for (int c = 0; c < 64; c++) {
            float xv = h1[c][k];
            const float4* wr = (const float4*)(W1t + c * 128 + g * 16);
#pragma unroll
            for (int q = 0; q < 4; q++) {
                float4 wv = wr[q];
                acc[q * 4 + 0] = fmaf(wv.x, xv, acc[q * 4 + 0]);
                acc[q * 4 + 1] = fmaf(wv.y, xv, acc[q * 4 + 1]);
                acc[q * 4 + 2] = fmaf(wv.z, xv, acc[q * 4 + 2]);
                acc[q * 4 + 3] = fmaf(wv.w, xv, acc[q * 4 + 3]);
            }
        }
#pragma unroll
        for (int i = 0; i < 16; i++) h2[g * 16 + i][k] = fmaxf(acc[i], 0.0f);
    }
    __syncthreads();

    // layer 3: 128 -> 256, o = g*32 + [0..32), then max over k (32-lane group reduce)
    {
        float acc[32];
#pragma unroll
        for (int i = 0; i < 32; i++) acc[i] = b2f[g * 32 + i];
        for (int c = 0; c < 128; c++) {
            float xv = h2[c][k];
            const float4* wr = (const float4*)(W2t + c * 256 + g * 32);
#pragma unroll
            for (int q = 0; q < 8; q++) {
                float4 wv = wr[q];
                acc[q * 4 + 0] = fmaf(wv.x, xv, acc[q * 4 + 0]);
                acc[q * 4 + 1] = fmaf(wv.y, xv, acc[q * 4 + 1]);
                acc[q * 4 + 2] = fmaf(wv.z, xv, acc[q * 4 + 2]);
                acc[q * 4 + 3] = fmaf(wv.w, xv, acc[q * 4 + 3]);
            }
        }
#pragma unroll
        for (int i = 0; i < 32; i++) {
            float v = fmaxf(acc[i], 0.0f);
#pragma unroll
            for (int off = 16; off >= 1; off >>= 1) v = fmaxf(v, __shfl_xor(v, off));
            if (k == 0) out_feat[((size_t)b * 256 + g * 32 + i) * NM + m] = v;
        }
    }
}

extern "C" void kernel_launch(void* const* d_in, const int* in_sizes, int n_in,
                              void* d_out, int out_size, void* d_ws, size_t ws_size,
                              hipStream_t stream) {
    const float* xyz   = (const float*)d_in[0];
    const float* feats = (const float*)d_in[1];
    const float* W0 = (const float*)d_in[2];  const float* b0 = (const float*)d_in[3];
    const float* s0 = (const float*)d_in[4];  const float* t0 = (const float*)d_in[5];
    const float* W1 = (const float*)d_in[6];  const float* b1 = (const float*)d_in[7];
    const float* s1 = (const float*)d_in[8];  const float* t1 = (const float*)d_in[9];
    const float* W2 = (const float*)d_in[10]; const float* b2 = (const float*)d_in[11];
    const float* s2 = (const float*)d_in[12]; const float* t2 = (const float*)d_in[13];

    float* ws_f = (float*)d_ws;
    int*   idx_ws  = (int*)(ws_f + WS_IDX);
    float* nxyz_ws = ws_f + WS_NXYZ;
    int*   ball_ws = (int*)(ws_f + WS_BALL);

    float* out_f = (float*)d_out;
    float* out_xyz  = out_f + OUT_XYZ;
    float* out_feat = out_f + OUT_FEAT;
    float* out_idxf = out_f + OUT_IDX;

    prep_weights<<<179, 256, 0, stream>>>(W0, b0, s0, t0, W1, b1, s1, t1, W2, b2, s2, t2, ws_f);
    fps_kernel<<<NB, 512, 0, stream>>>(xyz, idx_ws);
    gather_newxyz<<<32, 256, 0, stream>>>(xyz, idx_ws, nxyz_ws, out_xyz, out_idxf);
    ball_query_kernel<<<NB * NM, 256, 0, stream>>>(xyz, nxyz_ws, ball_ws);
    fused_mlp_kernel<<<NB * NM, 256, 0, stream>>>(xyz, feats, ws_f, ball_ws, nxyz_ws, out_feat);
}

// Round 3
// 2760.260 us; speedup vs baseline: 1.4276x; 1.1925x over previous
//
#include <hip/hip_runtime.h>
#include <stdint.h>

#define NB 8
#define NPT 16384
#define NM 1024
#define NK 32

// ws layout (float element offsets)
#define WS_W0T 0                    // 67*64 = 4288   W0t[c][o] = W0[o][c]*s0[o]
#define WS_B0  (WS_W0T + 4288)      // 64             b0*s0+t0
#define WS_W1T (WS_B0 + 64)         // 64*128 = 8192
#define WS_B1  (WS_W1T + 8192)      // 128
#define WS_W2T (WS_B1 + 128)        // 128*256 = 32768
#define WS_B2  (WS_W2T + 32768)     // 256
#define WS_IDX (WS_B2 + 256)        // 8192 ints (FPS indices)
#define WS_NXYZ (WS_IDX + 8192)     // 8*1024*3 = 24576 floats
#define WS_BALL (WS_NXYZ + 24576)   // 8*1024*32 = 262144 ints

// out layout (float element offsets)
#define OUT_XYZ 0
#define OUT_FEAT 24576
#define OUT_IDX (24576 + 2097152)

// ---------------- weight prep: transpose + fold BN scale ----------------
__global__ void prep_weights(const float* __restrict__ W0, const float* __restrict__ b0,
                             const float* __restrict__ s0, const float* __restrict__ t0,
                             const float* __restrict__ W1, const float* __restrict__ b1,
                             const float* __restrict__ s1, const float* __restrict__ t1,
                             const float* __restrict__ W2, const float* __restrict__ b2,
                             const float* __restrict__ s2, const float* __restrict__ t2,
                             float* __restrict__ ws) {
    int id = blockIdx.x * 256 + threadIdx.x;
    if (id < 4288) { int c = id >> 6, o = id & 63;  ws[WS_W0T + id] = W0[o * 67 + c] * s0[o]; return; }
    id -= 4288;
    if (id < 64)   { ws[WS_B0 + id] = fmaf(b0[id], s0[id], t0[id]); return; }
    id -= 64;
    if (id < 8192) { int c = id >> 7, o = id & 127; ws[WS_W1T + id] = W1[o * 64 + c] * s1[o]; return; }
    id -= 8192;
    if (id < 128)  { ws[WS_B1 + id] = fmaf(b1[id], s1[id], t1[id]); return; }
    id -= 128;
    if (id < 32768){ int c = id >> 8, o = id & 255; ws[WS_W2T + id] = W2[o * 128 + c] * s2[o]; return; }
    id -= 32768;
    if (id < 256)  { ws[WS_B2 + id] = fmaf(b2[id], s2[id], t2[id]); return; }
}

// ---------------- farthest point sampling ----------------
// One block per batch, 512 threads x 32 strided points pinned in VGPRs.
// asm-touch after each load kills LLVM's rematerialization (R2: VGPR=88 proved the
// compiler was re-loading all points from L2 every iteration instead of keeping them
// in registers). launch_bounds(512,2) gives the allocator a ~256-VGPR budget;
// 8 waves/block => 2 waves/SIMD, fine at ~200 VGPRs.
// Single barrier per iteration via parity-double-buffered s_red; packed u64 argmax
// (dist bits high, ~idx low => unsigned max = first-index-wins argmax).
// Distance math uses _rn intrinsics (no FMA contraction) to bit-match the reference.
__global__ __launch_bounds__(512, 2) void fps_kernel(const float* __restrict__ xyz,
                                                     int* __restrict__ out_idx) {
    int b = blockIdx.x, t = threadIdx.x;
    const float* __restrict__ Xp = xyz + (size_t)b * NPT * 3;
    float px[32], py[32], pz[32], dd[32];
#pragma unroll
    for (int j = 0; j < 32; j++) {
        int p = t + j * 512;
        px[j] = Xp[p * 3 + 0]; py[j] = Xp[p * 3 + 1]; pz[j] = Xp[p * 3 + 2];
        asm volatile("" : "+v"(px[j]), "+v"(py[j]), "+v"(pz[j]));  // pin in VGPRs
        dd[j] = 1e10f;
    }
    __shared__ uint64_t s_red[2][8];
    int farthest = 0;
    float cx = Xp[0], cy = Xp[1], cz = Xp[2];
    for (int it = 0; it < NM; ++it) {
        if (t == 0) out_idx[b * NM + it] = farthest;
        float best = -1.0f; int bi = 0;
#pragma unroll
        for (int j = 0; j < 32; j++) {
            float dx = __fsub_rn(px[j], cx);
            float dy = __fsub_rn(py[j], cy);
            float dz = __fsub_rn(pz[j], cz);
            float d  = __fadd_rn(__fadd_rn(__fmul_rn(dx, dx), __fmul_rn(dy, dy)), __fmul_rn(dz, dz));
            float dn = fminf(dd[j], d);
            dd[j] = dn;
            if (dn > best) { best = dn; bi = t + j * 512; }  // ascending j => first-max wins in-thread
        }
        // pack: high32 = dist bits (positive floats sort as uints), low32 = ~idx (tie -> lower idx)
        uint64_t pk = ((uint64_t)__float_as_uint(best) << 32) | (uint64_t)(uint32_t)(~(uint32_t)bi);
#pragma unroll
        for (int off = 32; off >= 1; off >>= 1) {
            uint64_t o = __shfl_xor(pk, off);
            if (o > pk) pk = o;
        }
        if ((t & 63) == 0) s_red[it & 1][t >> 6] = pk;
        __syncthreads();
        uint64_t m0 = s_red[it & 1][0];
#pragma unroll
        for (int w = 1; w < 8; w++) { uint64_t o = s_red[it & 1][w]; if (o > m0) m0 = o; }
        int widx = (int)(~(uint32_t)m0);
        farthest = widx;
        const float* cp = Xp + (size_t)widx * 3;   // same addr across wave -> broadcast, L2-hit
        cx = cp[0]; cy = cp[1]; cz = cp[2];
    }
}

// ---------------- gather new_xyz + emit indices as float ----------------
__global__ void gather_newxyz(const float* __restrict__ xyz, const int* __restrict__ idx_ws,
                              float* __restrict__ nxyz_ws, float* __restrict__ out_xyz,
                              float* __restrict__ out_idx_f) {
    int id = blockIdx.x * 256 + threadIdx.x;
    if (id >= NB * NM) return;
    int b = id / NM;
    int p = idx_ws[id];
    const float* Xp = xyz + ((size_t)b * NPT + p) * 3;
    float x = Xp[0], y = Xp[1], z = Xp[2];
    nxyz_ws[id * 3 + 0] = x; nxyz_ws[id * 3 + 1] = y; nxyz_ws[id * 3 + 2] = z;
    out_xyz[id * 3 + 0] = x; out_xyz[id * 3 + 1] = y; out_xyz[id * 3 + 2] = z;
    out_idx_f[id] = (float)p;
}

// ---------------- ball query: first 32 in-radius indices (ascending) ----------------
__global__ __launch_bounds__(256) void ball_query_kernel(const float* __restrict__ xyz,
                                                         const float* __restrict__ nxyz,
                                                         int* __restrict__ ball) {
    int blk = blockIdx.x;
    int b = blk >> 10;
    int t = threadIdx.x;
    const float* Xp = xyz + (size_t)b * NPT * 3;
    float cx = nxyz[blk * 3 + 0], cy = nxyz[blk * 3 + 1], cz = nxyz[blk * 3 + 2];
    const float r2 = (float)(0.4 * 0.4);
    uint64_t mask = 0;
    int base = t * 64;
    const float4* q = (const float4*)(Xp + (size_t)base * 3);
#pragma unroll 4
    for (int c = 0; c < 16; c++) {
        float4 A = q[c * 3 + 0], B = q[c * 3 + 1], C = q[c * 3 + 2];
        float xs[4] = {A.x, A.w, B.z, C.y};
        float ys[4] = {A.y, B.x, B.w, C.z};
        float zs[4] = {A.z, B.y, C.x, C.w};
#pragma unroll
        for (int u = 0; u < 4; u++) {
            float dx = __fsub_rn(xs[u], cx);
            float dy = __fsub_rn(ys[u], cy);
            float dz = __fsub_rn(zs[u], cz);
            float d2 = __fadd_rn(__fadd_rn(__fmul_rn(dx, dx), __fmul_rn(dy, dy)), __fmul_rn(dz, dz));
            if (d2 <= r2) mask |= (1ull << (c * 4 + u));
        }
    }
    int cnt = __popcll(mask);
    int scan = cnt;                       // wave inclusive scan
    for (int off = 1; off < 64; off <<= 1) {
        int nv = __shfl_up(scan, off);
        if ((t & 63) >= off) scan += nv;
    }
    __shared__ int s_wsum[4];
    __shared__ int s_hit[32];
    int w = t >> 6;
    if ((t & 63) == 63) s_wsum[w] = scan;
    __syncthreads();
    int woff = 0;
    for (int i = 0; i < 4; i++) if (i < w) woff += s_wsum[i];
    int excl = woff + scan - cnt;         // exclusive prefix in point-index order
    uint64_t mm = mask; int pos = excl;
    while (mm && pos < 32) {
        int j = __ffsll((long long)mm) - 1;
        s_hit[pos] = base + j;
        pos++;
        mm &= mm - 1;
    }
    __syncthreads();
    int total = s_wsum[0] + s_wsum[1] + s_wsum[2] + s_wsum[3];
    if (t < 32) {
        int first = s_hit[0];             // total >= 1 (center itself at d2=0)
        ball[blk * NK + t] = (t < total) ? s_hit[t] : first;
    }
}

// ---------------- fused group + 3xMLP + max over K ----------------
// TWO centers per block (halves per-block fixed cost, doubles fma:weight-load ratio).
// 256 threads: k = t&31, g = t>>5 in 0..7. LDS ~66KB -> 2 blocks/CU.
__global__ __launch_bounds__(256, 2) void fused_mlp_kernel(const float* __restrict__ xyz,
                                                           const float* __restrict__ feats,
                                                           const float* __restrict__ ws_f,
                                                           const int* __restrict__ ball,
                                                           const float* __restrict__ nxyz,
                                                           float* __restrict__ out_feat) {
    int blk = blockIdx.x;                  // 0..4095
    int b = blk >> 9;
    int m0 = (blk & 511) * 2;              // centers m0, m0+1
    int t = threadIdx.x;
    int k = t & 31, g = t >> 5;            // g in 0..7
    __shared__ float Xs[2][67][32];
    __shared__ float h1[2][64][32];
    __shared__ float h2[2][128][32];
    __shared__ int sidx[2][32];
    const float* W0t = ws_f + WS_W0T; const float* b0f = ws_f + WS_B0;
    const float* W1t = ws_f + WS_W1T; const float* b1f = ws_f + WS_B1;
    const float* W2t = ws_f + WS_W2T; const float* b2f = ws_f + WS_B2;

    if (t < 64) {
        int ctr = t >> 5;
        sidx[ctr][t & 31] = ball[((size_t)b * NM + m0 + ctr) * NK + (t & 31)];
    }
    __syncthreads();

    const float* Xp = xyz + (size_t)b * NPT * 3;
    if (g < 6) {
        int ctr = g / 3, dim = g % 3;
        float cc = nxyz[((size_t)b * NM + m0 + ctr) * 3 + dim];
        Xs[ctr][dim][k] = Xp[sidx[ctr][k] * 3 + dim] - cc;
    }
    const float* Fp = feats + (size_t)b * 64 * NPT;
#pragma unroll
    for (int i = 0; i < 8; i++) {
        int c = g + 8 * i;
        Xs[0][3 + c][k] = Fp[(size_t)c * NPT + sidx[0][k]];
        Xs[1][3 + c][k] = Fp[(size_t)c * NPT + sidx[1][k]];
    }
    __syncthreads();

    // layer 1: 67 -> 64, thread computes o = g*8 + [0..8) for both centers
    {
        float acc0[8], acc1[8];
#pragma unroll
        for (int i = 0; i < 8; i++) { acc0[i] = b0f[g * 8 + i]; acc1[i] = acc0[i]; }
#pragma unroll 4
        for (int c = 0; c < 67; c++) {
            float xv0 = Xs[0][c][k], xv1 = Xs[1][c][k];
            const float* wr = W0t + c * 64 + g * 8;
            float4 wa = *(const float4*)(wr), wb = *(const float4*)(wr + 4);
            acc0[0] = fmaf(wa.x, xv0, acc0[0]); acc1[0] = fmaf(wa.x, xv1, acc1[0]);
            acc0[1] = fmaf(wa.y, xv0, acc0[1]); acc1[1] = fmaf(wa.y, xv1, acc1[1]);
            acc0[2] = fmaf(wa.z, xv0, acc0[2]); acc1[2] = fmaf(wa.z, xv1, acc1[2]);
            acc0[3] = fmaf(wa.w, xv0, acc0[3]); acc1[3] = fmaf(wa.w, xv1, acc1[3]);
            acc0[4] = fmaf(wb.x, xv0, acc0[4]); acc1[4] = fmaf(wb.x, xv1, acc1[4]);
            acc0[5] = fmaf(wb.y, xv0, acc0[5]); acc1[5] = fmaf(wb.y, xv1, acc1[5]);
            acc0[6] = fmaf(wb.z, xv0, acc0[6]); acc1[6] = fmaf(wb.z, xv1, acc1[6]);
            acc0[7] = fmaf(wb.w, xv0, acc0[7]); acc1[7] = fmaf(wb.w, xv1, acc1[7]);
        }
#pragma unroll
        for (int i = 0; i < 8; i++) {
            h1[0][g * 8 + i][k] = fmaxf(acc0[i], 0.0f);
            h1[1][g * 8 + i][k] = fmaxf(acc1[i], 0.0f);
        }
    }
    __syncthreads();

    // layer 2: 64 -> 128, o = g*16 + [0..16)
    {
        float acc0[16], acc1[16];
#pragma unroll
        for (int i = 0; i < 16; i++) { acc0[i] = b1f[g * 16 + i]; acc1[i] = acc0[i]; }
#pragma unroll 4
        for (int c = 0; c < 64; c++) {
            float xv0 = h1[0][c][k], xv1 = h1[1][c][k];
            const float4* wr = (const float4*)(W1t + c * 128 + g * 16);
#pragma unroll
            for (int q = 0; q < 4; q++) {
                float4 wv = wr[q];
                acc0[q * 4 + 0] = fmaf(wv.x, xv0, acc0[q * 4 + 0]); acc1[q * 4 + 0] = fmaf(wv.x, xv1, acc1[q * 4 + 0]);
                acc0[q * 4 + 1] = fmaf(wv.y, xv0, acc0[q * 4 + 1]); acc1[q * 4 + 1] = fmaf(wv.y, xv1, acc1[q * 4 + 1]);
                acc0[q * 4 + 2] = fmaf(wv.z, xv0, acc0[q * 4 + 2]); acc1[q * 4 + 2] = fmaf(wv.z, xv1, acc1[q * 4 + 2]);
                acc0[q * 4 + 3] = fmaf(wv.w, xv0, acc0[q * 4 + 3]); acc1[q * 4 + 3] = fmaf(wv.w, xv1, acc1[q * 4 + 3]);
            }
        }
#pragma unroll
        for (int i = 0; i < 16; i++) {
            h2[0][g * 16 + i][k] = fmaxf(acc0[i], 0.0f);
            h2[1][g * 16 + i][k] = fmaxf(acc1[i], 0.0f);
        }
    }
    __syncthreads();

    // layer 3: 128 -> 256, o = g*32 + [0..32), then max over k (32-lane group reduce)
    {
        float acc0[32], acc1[32];
#pragma unroll
        for (int i = 0; i < 32; i++) { acc0[i] = b2f[g * 32 + i]; acc1[i] = acc0[i]; }
#pragma unroll 2
        for (int c = 0; c < 128; c++) {
            float xv0 = h2[0][c][k], xv1 = h2[1][c][k];
            const float4* wr = (const float4*)(W2t + c * 256 + g * 32);
#pragma unroll
            for (int q = 0; q < 8; q++) {
                float4 wv = wr[q];
                acc0[q * 4 + 0] = fmaf(wv.x, xv0, acc0[q * 4 + 0]); acc1[q * 4 + 0] = fmaf(wv.x, xv1, acc1[q * 4 + 0]);
                acc0[q * 4 + 1] = fmaf(wv.y, xv0, acc0[q * 4 + 1]); acc1[q * 4 + 1] = fmaf(wv.y, xv1, acc1[q * 4 + 1]);
                acc0[q * 4 + 2] = fmaf(wv.z, xv0, acc0[q * 4 + 2]); acc1[q * 4 + 2] = fmaf(wv.z, xv1, acc1[q * 4 + 2]);
                acc0[q * 4 + 3] = fmaf(wv.w, xv0, acc0[q * 4 + 3]); acc1[q * 4 + 3] = fmaf(wv.w, xv1, acc1[q * 4 + 3]);
            }
        }
#pragma unroll
        for (int i = 0; i < 32; i++) {
            float v0 = fmaxf(acc0[i], 0.0f);
            float v1 = fmaxf(acc1[i], 0.0f);
#pragma unroll
            for (int off = 16; off >= 1; off >>= 1) {
                v0 = fmaxf(v0, __shfl_xor(v0, off));
                v1 = fmaxf(v1, __shfl_xor(v1, off));
            }
            if (k == 0) {
                size_t o = (size_t)b * 256 + g * 32 + i;
                out_feat[o * NM + m0]     = v0;
                out_feat[o * NM + m0 + 1] = v1;
            }
        }
    }
}

extern "C" void kernel_launch(void* const* d_in, const int* in_sizes, int n_in,
                              void* d_out, int out_size, void* d_ws, size_t ws_size,
                              hipStream_t stream) {
    const float* xyz   = (const float*)d_in[0];
    const float* feats = (const float*)d_in[1];
    const float* W0 = (const float*)d_in[2];  const float* b0 = (const float*)d_in[3];
    const float* s0 = (const float*)d_in[4];  const float* t0 = (const float*)d_in[5];
    const float* W1 = (const float*)d_in[6];  const float* b1 = (const float*)d_in[7];
    const float* s1 = (const float*)d_in[8];  const float* t1 = (const float*)d_in[9];
    const float* W2 = (const float*)d_in[10]; const float* b2 = (const float*)d_in[11];
    const float* s2 = (const float*)d_in[12]; const float* t2 = (const float*)d_in[13];

    float* ws_f = (float*)d_ws;
    int*   idx_ws  = (int*)(ws_f + WS_IDX);
    float* nxyz_ws = ws_f + WS_NXYZ;
    int*   ball_ws = (int*)(ws_f + WS_BALL);

    float* out_f = (float*)d_out;
    float* out_xyz  = out_f + OUT_XYZ;
    float* out_feat = out_f + OUT_FEAT;
    float* out_idxf = out_f + OUT_IDX;

    prep_weights<<<179, 256, 0, stream>>>(W0, b0, s0, t0, W1, b1, s1, t1, W2, b2, s2, t2, ws_f);
    fps_kernel<<<NB, 512, 0, stream>>>(xyz, idx_ws);
    gather_newxyz<<<32, 256, 0, stream>>>(xyz, idx_ws, nxyz_ws, out_xyz, out_idxf);
    ball_query_kernel<<<NB * NM, 256, 0, stream>>>(xyz, nxyz_ws, ball_ws);
    fused_mlp_kernel<<<NB * NM / 2, 256, 0, stream>>>(xyz, feats, ws_f, ball_ws, nxyz_ws, out_feat);
}